// Round 6
// baseline (1968.580 us; speedup 1.0000x reference)
//
#include <hip/hip_runtime.h>

#define NUM_USERS 100000
#define NUM_ITEMS 50000
#define N_NODES   150000   // NUM_USERS + NUM_ITEMS
#define DIM       64
#define NUM_EDGES 2000000

#define NBIN          512
#define COLS_PER_BIN  ((N_NODES + NBIN - 1) / NBIN)   // 293
#define BINCAP        6144                            // >> 2M/512=3906 (+36 sigma)

#define SCAN_THREADS 256
#define SCAN_ITEMS   8
#define SCAN_CHUNK   (SCAN_THREADS * SCAN_ITEMS)               // 2048
#define SCAN_NBLK    ((N_NODES + SCAN_CHUNK - 1) / SCAN_CHUNK) // 74

// ---------------------------------------------------------------------------
// Fused: integer degree histogram + coarse binning of edges.
// 512 bins -> only 512 live write frontiers -> binbuf lines fill while L2
// resident (vs 150K frontiers in the old ticket scatter = 8x writebacks).
__global__ void histbin_kernel(const int* __restrict__ row,
                               const int* __restrict__ col,
                               int* __restrict__ deg,
                               int* __restrict__ bincnt,
                               int2* __restrict__ binbuf, int nE) {
    int stride = gridDim.x * blockDim.x;
    for (int e = blockIdx.x * blockDim.x + threadIdx.x; e < nE; e += stride) {
        int c = col[e];
        int r = row[e];
        atomicAdd(&deg[c], 1);
        int b = c / COLS_PER_BIN;
        int p = atomicAdd(&bincnt[b], 1);
        if (p < BINCAP)                       // statistically never false
            binbuf[(size_t)b * BINCAP + p] = make_int2(r, c);
    }
}

// dinv[i] = deg>0 ? 1/sqrt(deg) : 0
__global__ void dinv_kernel(const int* __restrict__ deg,
                            float* __restrict__ dinv, int n) {
    int stride = gridDim.x * blockDim.x;
    for (int i = blockIdx.x * blockDim.x + threadIdx.x; i < n; i += stride) {
        float d = (float)deg[i];
        dinv[i] = (d > 0.0f) ? (1.0f / sqrtf(d)) : 0.0f;
    }
}

// ---- exclusive scan of deg -> col_ptr (3 kernels) ----
__global__ void scanA_kernel(const int* __restrict__ deg,
                             int* __restrict__ colptr,
                             int* __restrict__ bsum) {
    __shared__ int s[SCAN_THREADS];
    int t = threadIdx.x;
    int base = blockIdx.x * SCAN_CHUNK + t * SCAN_ITEMS;
    int items[SCAN_ITEMS];
    int mysum = 0;
    #pragma unroll
    for (int j = 0; j < SCAN_ITEMS; ++j) {
        int idx = base + j;
        items[j] = (idx < N_NODES) ? deg[idx] : 0;
        mysum += items[j];
    }
    s[t] = mysum;
    __syncthreads();
    for (int off = 1; off < SCAN_THREADS; off <<= 1) {
        int v = (t >= off) ? s[t - off] : 0;
        __syncthreads();
        s[t] += v;
        __syncthreads();
    }
    int excl = s[t] - mysum;
    if (t == SCAN_THREADS - 1) bsum[blockIdx.x] = s[t];
    int run = excl;
    #pragma unroll
    for (int j = 0; j < SCAN_ITEMS; ++j) {
        int idx = base + j;
        if (idx < N_NODES) colptr[idx] = run;
        run += items[j];
    }
}

__global__ void scanB_kernel(int* __restrict__ bsum,
                             int* __restrict__ boff,
                             int* __restrict__ colptr) {
    if (threadIdx.x == 0) {
        int run = 0;
        for (int b = 0; b < SCAN_NBLK; ++b) {
            boff[b] = run;
            run += bsum[b];
        }
        colptr[N_NODES] = run;
    }
}

__global__ void scanC_kernel(int* __restrict__ colptr,
                             const int* __restrict__ boff) {
    int t = threadIdx.x;
    int off = boff[blockIdx.x];
    int base = blockIdx.x * SCAN_CHUNK + t * SCAN_ITEMS;
    #pragma unroll
    for (int j = 0; j < SCAN_ITEMS; ++j) {
        int idx = base + j;
        if (idx < N_NODES) colptr[idx] += off;
    }
}

// ---------------------------------------------------------------------------
// Fine scatter within one bin per block. Cursors + dinv[col] in LDS; EDATA
// writes confined to the bin's ~250KB window -> stays L2-resident -> 16MB
// total writeback instead of 128MB.
__global__ void binscatter_kernel(const int2* __restrict__ binbuf,
                                  const int* __restrict__ bincnt,
                                  const int* __restrict__ colptr,
                                  const float* __restrict__ dinv,
                                  int2* __restrict__ edata) {
    __shared__ int   cur[COLS_PER_BIN];
    __shared__ float dlds[COLS_PER_BIN];
    int b  = blockIdx.x;
    int lo = b * COLS_PER_BIN;
    int ncols = N_NODES - lo; if (ncols > COLS_PER_BIN) ncols = COLS_PER_BIN;
    for (int i = threadIdx.x; i < ncols; i += blockDim.x) {
        cur[i]  = colptr[lo + i];     // global EDATA position
        dlds[i] = dinv[lo + i];
    }
    __syncthreads();
    int cnt = bincnt[b]; if (cnt > BINCAP) cnt = BINCAP;
    const int2* src = binbuf + (size_t)b * BINCAP;
    for (int i = threadIdx.x; i < cnt; i += blockDim.x) {
        int2 rc = src[i];
        int li = rc.y - lo;
        int t = atomicAdd(&cur[li], 1);          // LDS atomic
        edata[t] = make_int2(rc.x, __float_as_int(dinv[rc.x] * dlds[li]));
    }
}

// ---------------------------------------------------------------------------
// CSR gather conv, 4 edges in flight per wave (unchanged from R5).
template <int MODE>
__global__ void conv_kernel(const float4* __restrict__ xin,
                            const int* __restrict__ colptr,
                            const int2* __restrict__ edata,
                            const float4* __restrict__ a0,
                            const float4* __restrict__ a1,
                            const float4* __restrict__ a2,
                            float4* __restrict__ out) {
    int lane = threadIdx.x & 63;
    int node = (blockIdx.x * blockDim.x + threadIdx.x) >> 6;
    if (node >= N_NODES) return;
    int grp = lane >> 4;
    int l16 = lane & 15;
    int s = colptr[node];
    int t = colptr[node + 1];
    float4 acc = make_float4(0.0f, 0.0f, 0.0f, 0.0f);
    for (int e = s + grp; e < t; e += 4) {
        int2 ed = edata[e];
        float nm = __int_as_float(ed.y);
        float4 v = xin[ed.x * 16 + l16];
        acc.x = fmaf(v.x, nm, acc.x);
        acc.y = fmaf(v.y, nm, acc.y);
        acc.z = fmaf(v.z, nm, acc.z);
        acc.w = fmaf(v.w, nm, acc.w);
    }
    acc.x += __shfl_xor(acc.x, 16); acc.y += __shfl_xor(acc.y, 16);
    acc.z += __shfl_xor(acc.z, 16); acc.w += __shfl_xor(acc.w, 16);
    acc.x += __shfl_xor(acc.x, 32); acc.y += __shfl_xor(acc.y, 32);
    acc.z += __shfl_xor(acc.z, 32); acc.w += __shfl_xor(acc.w, 32);
    if (grp == 0) {
        int o = node * 16 + l16;
        if (MODE == 0) {
            out[o] = acc;
        } else if (MODE == 1) {
            float4 p = a0[o], q = a1[o];
            const float sc = 1.0f / 3.0f;
            out[o] = make_float4((p.x + q.x + acc.x) * sc,
                                 (p.y + q.y + acc.y) * sc,
                                 (p.z + q.z + acc.z) * sc,
                                 (p.w + q.w + acc.w) * sc);
        } else {
            float4 p = a0[o], q = a1[o], g = a2[o];
            const float sc = 1.0f / 3.0f;
            out[o] = make_float4(g.x + (p.x + q.x + acc.x) * sc,
                                 g.y + (p.y + q.y + acc.y) * sc,
                                 g.z + (p.z + q.z + acc.z) * sc,
                                 g.w + (p.w + q.w + acc.w) * sc);
        }
    }
}

// Wt[k][j] = W[j][k] for both weight matrices (single block)
__global__ void transpose_w_kernel(const float* __restrict__ Wu,
                                   const float* __restrict__ Wi,
                                   float* __restrict__ WtU,
                                   float* __restrict__ WtI) {
    for (int t = threadIdx.x; t < DIM * DIM; t += blockDim.x) {
        int j = t >> 6, k = t & 63;
        WtU[k * DIM + j] = Wu[t];
        WtI[k * DIM + j] = Wi[t];
    }
}

// dst[i][j] = sum_k src[i][k] * Wt[k][j], Wt chosen per row (user vs item)
__global__ void matmul_kernel(const float* __restrict__ src,
                              const float* __restrict__ WtU,
                              const float* __restrict__ WtI,
                              float* __restrict__ dst) {
    __shared__ float rows[4][DIM];
    int lane = threadIdx.x & 63;
    int g = threadIdx.x >> 6;
    int totalGroups = N_NODES / 4;
    for (int blk = blockIdx.x; blk < totalGroups; blk += gridDim.x) {
        int i = blk * 4 + g;
        rows[g][lane] = src[(size_t)i * DIM + lane];
        __syncthreads();
        const float* Wt = (i < NUM_USERS) ? WtU : WtI;
        float acc = 0.0f;
        #pragma unroll
        for (int k = 0; k < DIM; ++k)
            acc = fmaf(rows[g][k], Wt[k * DIM + lane], acc);
        dst[(size_t)i * DIM + lane] = acc;
        __syncthreads();
    }
}

// ---------------------------------------------------------------------------
extern "C" void kernel_launch(void* const* d_in, const int* in_sizes, int n_in,
                              void* d_out, int out_size, void* d_ws, size_t ws_size,
                              hipStream_t stream) {
    const float* user_emb = (const float*)d_in[0];
    const float* item_emb = (const float*)d_in[1];
    const float* W_user   = (const float*)d_in[2];
    const float* W_item   = (const float*)d_in[3];
    const int*   ec       = (const int*)d_in[4];   // [2][NUM_EDGES]
    const int*   er       = (const int*)d_in[5];
    const int* cart_row = ec;
    const int* cart_col = ec + NUM_EDGES;
    const int* rent_row = er;
    const int* rent_col = er + NUM_EDGES;
    float* out = (float*)d_out;

    const size_t NV = (size_t)N_NODES * DIM;       // 9.6M floats
    float* ws    = (float*)d_ws;
    float* X     = ws;                  // node features / rent_init
    float* H1    = X    + NV;           // also reused as binbuf during CSR build
    float* CART  = H1   + NV;
    float* DINV  = CART + NV;
    int*   DEG   = (int*)(DINV + 150016);
    int*   BINCNT= DEG  + 150016;       // adjacent -> single memset with DEG
    int*   CPTR  = BINCNT + 512;
    int*   BSUM  = CPTR + 150016;
    int*   BOFF  = BSUM + 128;
    float* WtU   = (float*)(BOFF + 128);
    float* WtI   = WtU + DIM * DIM;
    int2*  EDATA = (int2*)(WtI + DIM * DIM);       // 2M int2 = 16 MB
    int2*  BINBUF= (int2*)H1;                      // 512*6144*8B = 25MB < 38MB

    const int BLOCKS = 2048, THREADS = 256;
    const int CONV_BLOCKS = (N_NODES + 3) / 4;     // 4 waves (nodes) per block

    // x0 = concat(user_emb, item_emb)
    hipMemcpyAsync(X, user_emb, (size_t)NUM_USERS * DIM * sizeof(float),
                   hipMemcpyDeviceToDevice, stream);
    hipMemcpyAsync(X + (size_t)NUM_USERS * DIM, item_emb,
                   (size_t)NUM_ITEMS * DIM * sizeof(float),
                   hipMemcpyDeviceToDevice, stream);
    transpose_w_kernel<<<1, 256, 0, stream>>>(W_user, W_item, WtU, WtI);

    // ================= behavior 1: cart =================
    hipMemsetAsync(DEG, 0, (150016 + 512) * sizeof(int), stream);
    histbin_kernel<<<BLOCKS, THREADS, 0, stream>>>(cart_row, cart_col,
                                                   DEG, BINCNT, BINBUF, NUM_EDGES);
    dinv_kernel<<<(N_NODES + 255) / 256, 256, 0, stream>>>(DEG, DINV, N_NODES);
    scanA_kernel<<<SCAN_NBLK, SCAN_THREADS, 0, stream>>>(DEG, CPTR, BSUM);
    scanB_kernel<<<1, 64, 0, stream>>>(BSUM, BOFF, CPTR);
    scanC_kernel<<<SCAN_NBLK, SCAN_THREADS, 0, stream>>>(CPTR, BOFF);
    binscatter_kernel<<<NBIN, THREADS, 0, stream>>>(BINBUF, BINCNT, CPTR, DINV, EDATA);

    // layer 1: H1 = conv(X); layer 2 fused with combine: CART = (X+H1+conv(H1))/3
    conv_kernel<0><<<CONV_BLOCKS, 256, 0, stream>>>((const float4*)X, CPTR, EDATA,
                                                    nullptr, nullptr, nullptr,
                                                    (float4*)H1);
    conv_kernel<1><<<CONV_BLOCKS, 256, 0, stream>>>((const float4*)H1, CPTR, EDATA,
                                                    (const float4*)X, (const float4*)H1,
                                                    nullptr, (float4*)CART);

    // ---- projection: X = CART @ W^T (per-row user/item) ----
    matmul_kernel<<<BLOCKS, THREADS, 0, stream>>>(CART, WtU, WtI, X);

    // ================= behavior 2: rent =================
    hipMemsetAsync(DEG, 0, (150016 + 512) * sizeof(int), stream);
    histbin_kernel<<<BLOCKS, THREADS, 0, stream>>>(rent_row, rent_col,
                                                   DEG, BINCNT, BINBUF, NUM_EDGES);
    dinv_kernel<<<(N_NODES + 255) / 256, 256, 0, stream>>>(DEG, DINV, N_NODES);
    scanA_kernel<<<SCAN_NBLK, SCAN_THREADS, 0, stream>>>(DEG, CPTR, BSUM);
    scanB_kernel<<<1, 64, 0, stream>>>(BSUM, BOFF, CPTR);
    scanC_kernel<<<SCAN_NBLK, SCAN_THREADS, 0, stream>>>(CPTR, BOFF);
    binscatter_kernel<<<NBIN, THREADS, 0, stream>>>(BINBUF, BINCNT, CPTR, DINV, EDATA);

    // layer 1: H1 = conv(X); layer 2 fused with final: out = CART + (X+H1+conv(H1))/3
    conv_kernel<0><<<CONV_BLOCKS, 256, 0, stream>>>((const float4*)X, CPTR, EDATA,
                                                    nullptr, nullptr, nullptr,
                                                    (float4*)H1);
    conv_kernel<2><<<CONV_BLOCKS, 256, 0, stream>>>((const float4*)H1, CPTR, EDATA,
                                                    (const float4*)X, (const float4*)H1,
                                                    (const float4*)CART, (float4*)out);
}

// Round 7
// 1062.853 us; speedup vs baseline: 1.8522x; 1.8522x over previous
//
#include <hip/hip_runtime.h>

#define NUM_USERS 100000
#define NUM_ITEMS 50000
#define N_NODES   150000   // NUM_USERS + NUM_ITEMS
#define DIM       64
#define NUM_EDGES 2000000

#define CONV_GRID ((N_NODES + 3) / 4)   // 37500 blocks, 4 nodes (waves) per block
#define HIST_XBLK 512                    // extra blocks fused for rent histogram
#define SCAT_XBLK 1024                   // extra blocks fused for rent scatter

#define SCAN_THREADS 256
#define SCAN_ITEMS   8
#define SCAN_CHUNK   (SCAN_THREADS * SCAN_ITEMS)               // 2048
#define SCAN_NBLK    ((N_NODES + SCAN_CHUNK - 1) / SCAN_CHUNK) // 74

// ---------------------------------------------------------------------------
// integer degree histogram (2M atomics over 150K addresses: low contention --
// R6 lesson: never funnel onto few counters)
__global__ void deghist_kernel(const int* __restrict__ col,
                               int* __restrict__ deg, int nE) {
    int stride = gridDim.x * blockDim.x;
    for (int e = blockIdx.x * blockDim.x + threadIdx.x; e < nE; e += stride)
        atomicAdd(&deg[col[e]], 1);
}

// dinv[i] = deg>0 ? 1/sqrt(deg) : 0
__global__ void dinv_kernel(const int* __restrict__ deg,
                            float* __restrict__ dinv, int n) {
    int stride = gridDim.x * blockDim.x;
    for (int i = blockIdx.x * blockDim.x + threadIdx.x; i < n; i += stride) {
        float d = (float)deg[i];
        dinv[i] = (d > 0.0f) ? (1.0f / sqrtf(d)) : 0.0f;
    }
}

// ---- exclusive scan of deg -> col_ptr (3 kernels) ----
__global__ void scanA_kernel(const int* __restrict__ deg,
                             int* __restrict__ colptr,
                             int* __restrict__ bsum) {
    __shared__ int s[SCAN_THREADS];
    int t = threadIdx.x;
    int base = blockIdx.x * SCAN_CHUNK + t * SCAN_ITEMS;
    int items[SCAN_ITEMS];
    int mysum = 0;
    #pragma unroll
    for (int j = 0; j < SCAN_ITEMS; ++j) {
        int idx = base + j;
        items[j] = (idx < N_NODES) ? deg[idx] : 0;
        mysum += items[j];
    }
    s[t] = mysum;
    __syncthreads();
    for (int off = 1; off < SCAN_THREADS; off <<= 1) {
        int v = (t >= off) ? s[t - off] : 0;
        __syncthreads();
        s[t] += v;
        __syncthreads();
    }
    int excl = s[t] - mysum;
    if (t == SCAN_THREADS - 1) bsum[blockIdx.x] = s[t];
    int run = excl;
    #pragma unroll
    for (int j = 0; j < SCAN_ITEMS; ++j) {
        int idx = base + j;
        if (idx < N_NODES) colptr[idx] = run;
        run += items[j];
    }
}

__global__ void scanB_kernel(int* __restrict__ bsum,
                             int* __restrict__ boff,
                             int* __restrict__ colptr) {
    if (threadIdx.x == 0) {
        int run = 0;
        for (int b = 0; b < SCAN_NBLK; ++b) {
            boff[b] = run;
            run += bsum[b];
        }
        colptr[N_NODES] = run;
    }
}

__global__ void scanC_kernel(int* __restrict__ colptr,
                             int* __restrict__ cursor,
                             const int* __restrict__ boff) {
    int t = threadIdx.x;
    int off = boff[blockIdx.x];
    int base = blockIdx.x * SCAN_CHUNK + t * SCAN_ITEMS;
    #pragma unroll
    for (int j = 0; j < SCAN_ITEMS; ++j) {
        int idx = base + j;
        if (idx < N_NODES) {
            int v = colptr[idx] + off;
            colptr[idx] = v;
            cursor[idx] = v;
        }
    }
}

// ticket scatter: edata[p] = row  (4B payload; norm factored out into conv)
__device__ __forceinline__ void scatter_body(int xblk, int nXblk,
                                             const int* __restrict__ row,
                                             const int* __restrict__ col,
                                             int* __restrict__ cursor,
                                             int* __restrict__ edata) {
    int stride = nXblk * 256;
    for (int e = xblk * 256 + (int)threadIdx.x; e < NUM_EDGES; e += stride) {
        int c = col[e];
        int p = atomicAdd(&cursor[c], 1);
        edata[p] = row[e];
    }
}

__global__ void edgescatter_kernel(const int* __restrict__ row,
                                   const int* __restrict__ col,
                                   int* __restrict__ cursor,
                                   int* __restrict__ edata) {
    scatter_body(blockIdx.x, gridDim.x, row, col, cursor, edata);
}

// ---------------------------------------------------------------------------
// CSR gather conv body. Wave = one node; 4 groups x 16 lanes; 4 edges in
// flight; per-edge weight dinv[r], epilogue x dinv[node].
// MODE 0: out = dc*sum ; MODE 1: out = (a0+a1+dc*sum)/3 ;
// MODE 2: out = a2 + (a0+a1+dc*sum)/3
template <int MODE>
__device__ __forceinline__ void conv_body(int cblk,
                                          const float4* __restrict__ xin,
                                          const int* __restrict__ colptr,
                                          const int* __restrict__ edata,
                                          const float* __restrict__ dinv,
                                          const float4* __restrict__ a0,
                                          const float4* __restrict__ a1,
                                          const float4* __restrict__ a2,
                                          float4* __restrict__ out) {
    int lane = threadIdx.x & 63;
    int node = cblk * 4 + (threadIdx.x >> 6);
    if (node >= N_NODES) return;
    int grp = lane >> 4;
    int l16 = lane & 15;
    int s = colptr[node];
    int t = colptr[node + 1];
    float4 acc = make_float4(0.0f, 0.0f, 0.0f, 0.0f);
    for (int e = s + grp; e < t; e += 4) {
        int r = edata[e];                     // broadcast within 16-lane group
        float dr = dinv[r];                   // L2-resident 600KB array
        float4 v = xin[r * 16 + l16];         // 16 lanes x 16B = 256B gather
        acc.x = fmaf(v.x, dr, acc.x);
        acc.y = fmaf(v.y, dr, acc.y);
        acc.z = fmaf(v.z, dr, acc.z);
        acc.w = fmaf(v.w, dr, acc.w);
    }
    acc.x += __shfl_xor(acc.x, 16); acc.y += __shfl_xor(acc.y, 16);
    acc.z += __shfl_xor(acc.z, 16); acc.w += __shfl_xor(acc.w, 16);
    acc.x += __shfl_xor(acc.x, 32); acc.y += __shfl_xor(acc.y, 32);
    acc.z += __shfl_xor(acc.z, 32); acc.w += __shfl_xor(acc.w, 32);
    if (grp == 0) {
        float dc = dinv[node];
        int o = node * 16 + l16;
        if (MODE == 0) {
            out[o] = make_float4(dc * acc.x, dc * acc.y, dc * acc.z, dc * acc.w);
        } else if (MODE == 1) {
            float4 p = a0[o], q = a1[o];
            const float sc = 1.0f / 3.0f;
            out[o] = make_float4((p.x + q.x + dc * acc.x) * sc,
                                 (p.y + q.y + dc * acc.y) * sc,
                                 (p.z + q.z + dc * acc.z) * sc,
                                 (p.w + q.w + dc * acc.w) * sc);
        } else {
            float4 p = a0[o], q = a1[o], g = a2[o];
            const float sc = 1.0f / 3.0f;
            out[o] = make_float4(g.x + (p.x + q.x + dc * acc.x) * sc,
                                 g.y + (p.y + q.y + dc * acc.y) * sc,
                                 g.z + (p.z + q.z + dc * acc.z) * sc,
                                 g.w + (p.w + q.w + dc * acc.w) * sc);
        }
    }
}

// standalone convs (rent behavior)
__global__ void conv0_kernel(const float4* __restrict__ xin,
                             const int* __restrict__ colptr,
                             const int* __restrict__ edata,
                             const float* __restrict__ dinv,
                             float4* __restrict__ out) {
    conv_body<0>(blockIdx.x, xin, colptr, edata, dinv,
                 nullptr, nullptr, nullptr, out);
}

__global__ void conv2_kernel(const float4* __restrict__ xin,
                             const int* __restrict__ colptr,
                             const int* __restrict__ edata,
                             const float* __restrict__ dinv,
                             const float4* __restrict__ a0,
                             const float4* __restrict__ a1,
                             const float4* __restrict__ a2,
                             float4* __restrict__ out) {
    conv_body<2>(blockIdx.x, xin, colptr, edata, dinv, a0, a1, a2, out);
}

// FUSED: cart conv1 (blocks < CONV_GRID) + rent degree histogram (extra blocks)
// Disjoint buffers -> no races; overlaps gather-bound conv with atomic-bound hist.
__global__ void conv0_hist_kernel(const float4* __restrict__ xin,
                                  const int* __restrict__ colptr,
                                  const int* __restrict__ edata,
                                  const float* __restrict__ dinv,
                                  float4* __restrict__ out,
                                  const int* __restrict__ hcol,
                                  int* __restrict__ hdeg) {
    if (blockIdx.x < CONV_GRID) {
        conv_body<0>(blockIdx.x, xin, colptr, edata, dinv,
                     nullptr, nullptr, nullptr, out);
    } else {
        int b = blockIdx.x - CONV_GRID;
        int stride = HIST_XBLK * 256;
        for (int e = b * 256 + (int)threadIdx.x; e < NUM_EDGES; e += stride)
            atomicAdd(&hdeg[hcol[e]], 1);
    }
}

// FUSED: cart conv2+combine (blocks < CONV_GRID) + rent edge scatter (extra)
__global__ void conv1_scat_kernel(const float4* __restrict__ xin,
                                  const int* __restrict__ colptr,
                                  const int* __restrict__ edata,
                                  const float* __restrict__ dinv,
                                  const float4* __restrict__ a0,
                                  const float4* __restrict__ a1,
                                  float4* __restrict__ out,
                                  const int* __restrict__ srow,
                                  const int* __restrict__ scol,
                                  int* __restrict__ scursor,
                                  int* __restrict__ sedata) {
    if (blockIdx.x < CONV_GRID) {
        conv_body<1>(blockIdx.x, xin, colptr, edata, dinv,
                     a0, a1, nullptr, out);
    } else {
        scatter_body(blockIdx.x - CONV_GRID, SCAT_XBLK, srow, scol,
                     scursor, sedata);
    }
}

// Wt[k][j] = W[j][k] for both weight matrices (single block)
__global__ void transpose_w_kernel(const float* __restrict__ Wu,
                                   const float* __restrict__ Wi,
                                   float* __restrict__ WtU,
                                   float* __restrict__ WtI) {
    for (int t = threadIdx.x; t < DIM * DIM; t += blockDim.x) {
        int j = t >> 6, k = t & 63;
        WtU[k * DIM + j] = Wu[t];
        WtI[k * DIM + j] = Wi[t];
    }
}

// dst[i][j] = sum_k src[i][k] * Wt[k][j], Wt chosen per row (user vs item)
__global__ void matmul_kernel(const float* __restrict__ src,
                              const float* __restrict__ WtU,
                              const float* __restrict__ WtI,
                              float* __restrict__ dst) {
    __shared__ float rows[4][DIM];
    int lane = threadIdx.x & 63;
    int g = threadIdx.x >> 6;
    int totalGroups = N_NODES / 4;
    for (int blk = blockIdx.x; blk < totalGroups; blk += gridDim.x) {
        int i = blk * 4 + g;
        rows[g][lane] = src[(size_t)i * DIM + lane];
        __syncthreads();
        const float* Wt = (i < NUM_USERS) ? WtU : WtI;
        float acc = 0.0f;
        #pragma unroll
        for (int k = 0; k < DIM; ++k)
            acc = fmaf(rows[g][k], Wt[k * DIM + lane], acc);
        dst[(size_t)i * DIM + lane] = acc;
        __syncthreads();
    }
}

// ---------------------------------------------------------------------------
extern "C" void kernel_launch(void* const* d_in, const int* in_sizes, int n_in,
                              void* d_out, int out_size, void* d_ws, size_t ws_size,
                              hipStream_t stream) {
    const float* user_emb = (const float*)d_in[0];
    const float* item_emb = (const float*)d_in[1];
    const float* W_user   = (const float*)d_in[2];
    const float* W_item   = (const float*)d_in[3];
    const int*   ec       = (const int*)d_in[4];   // [2][NUM_EDGES]
    const int*   er       = (const int*)d_in[5];
    const int* cart_row = ec;
    const int* cart_col = ec + NUM_EDGES;
    const int* rent_row = er;
    const int* rent_col = er + NUM_EDGES;
    float* out = (float*)d_out;

    const size_t NV = (size_t)N_NODES * DIM;       // 9.6M floats
    const int NPAD = 150016;
    float* ws     = (float*)d_ws;
    float* X      = ws;                 // features; becomes rent_init after matmul
    float* H1     = X     + NV;
    float* CART   = H1    + NV;
    float* DINVC  = CART  + NV;
    float* DINVR  = DINVC + NPAD;
    int*   DEGC   = (int*)(DINVR + NPAD);
    int*   DEGR   = DEGC  + NPAD;       // adjacent -> single memset for both
    int*   CPTRC  = DEGR  + NPAD;
    int*   CURSC  = CPTRC + NPAD;
    int*   CPTRR  = CURSC + NPAD;
    int*   CURSR  = CPTRR + NPAD;
    int*   BSUM   = CURSR + NPAD;
    int*   BOFF   = BSUM  + 128;
    float* WtU    = (float*)(BOFF + 128);
    float* WtI    = WtU + DIM * DIM;
    int*   EDATAC = (int*)(WtI + DIM * DIM);   // 2M int = 8 MB
    int*   EDATAR = EDATAC + NUM_EDGES;

    const int BLOCKS = 2048, THREADS = 256;

    // x0 = concat(user_emb, item_emb)
    hipMemcpyAsync(X, user_emb, (size_t)NUM_USERS * DIM * sizeof(float),
                   hipMemcpyDeviceToDevice, stream);
    hipMemcpyAsync(X + (size_t)NUM_USERS * DIM, item_emb,
                   (size_t)NUM_ITEMS * DIM * sizeof(float),
                   hipMemcpyDeviceToDevice, stream);
    transpose_w_kernel<<<1, 256, 0, stream>>>(W_user, W_item, WtU, WtI);
    hipMemsetAsync(DEGC, 0, 2 * NPAD * sizeof(int), stream);   // both behaviors

    // ---- cart CSR build ----
    deghist_kernel<<<BLOCKS, THREADS, 0, stream>>>(cart_col, DEGC, NUM_EDGES);
    dinv_kernel<<<(N_NODES + 255) / 256, 256, 0, stream>>>(DEGC, DINVC, N_NODES);
    scanA_kernel<<<SCAN_NBLK, SCAN_THREADS, 0, stream>>>(DEGC, CPTRC, BSUM);
    scanB_kernel<<<1, 64, 0, stream>>>(BSUM, BOFF, CPTRC);
    scanC_kernel<<<SCAN_NBLK, SCAN_THREADS, 0, stream>>>(CPTRC, CURSC, BOFF);
    edgescatter_kernel<<<BLOCKS, THREADS, 0, stream>>>(cart_row, cart_col,
                                                       CURSC, EDATAC);

    // cart conv1 (X->H1)  FUSED with rent degree histogram
    conv0_hist_kernel<<<CONV_GRID + HIST_XBLK, 256, 0, stream>>>(
        (const float4*)X, CPTRC, EDATAC, DINVC, (float4*)H1,
        rent_col, DEGR);

    // rent dinv + scan (needs DEGR from fused kernel above)
    dinv_kernel<<<(N_NODES + 255) / 256, 256, 0, stream>>>(DEGR, DINVR, N_NODES);
    scanA_kernel<<<SCAN_NBLK, SCAN_THREADS, 0, stream>>>(DEGR, CPTRR, BSUM);
    scanB_kernel<<<1, 64, 0, stream>>>(BSUM, BOFF, CPTRR);
    scanC_kernel<<<SCAN_NBLK, SCAN_THREADS, 0, stream>>>(CPTRR, CURSR, BOFF);

    // cart conv2 + combine (CART = (X+H1+conv(H1))/3)  FUSED with rent scatter
    conv1_scat_kernel<<<CONV_GRID + SCAT_XBLK, 256, 0, stream>>>(
        (const float4*)H1, CPTRC, EDATAC, DINVC,
        (const float4*)X, (const float4*)H1, (float4*)CART,
        rent_row, rent_col, CURSR, EDATAR);

    // projection: X = CART @ W^T (per-row user/item)
    matmul_kernel<<<BLOCKS, THREADS, 0, stream>>>(CART, WtU, WtI, X);

    // rent conv1 (X->H1)
    conv0_kernel<<<CONV_GRID, 256, 0, stream>>>((const float4*)X, CPTRR, EDATAR,
                                                DINVR, (float4*)H1);
    // rent conv2 + final: out = CART + (X+H1+conv(H1))/3
    conv2_kernel<<<CONV_GRID, 256, 0, stream>>>((const float4*)H1, CPTRR, EDATAR,
                                                DINVR,
                                                (const float4*)X, (const float4*)H1,
                                                (const float4*)CART, (float4*)out);
}

// Round 8
// 964.759 us; speedup vs baseline: 2.0405x; 1.1017x over previous
//
#include <hip/hip_runtime.h>

#define NUM_USERS 100000
#define NUM_ITEMS 50000
#define N_NODES   150000   // NUM_USERS + NUM_ITEMS
#define DIM       64
#define NUM_EDGES 2000000
#define NPAD      150016

#define CONV_GRID ((N_NODES + 3) / 4)   // 4 nodes (waves) per 256-thr block

#define SCAN_THREADS 256
#define SCAN_ITEMS   8
#define SCAN_CHUNK   (SCAN_THREADS * SCAN_ITEMS)               // 2048
#define SCAN_NBLK    ((N_NODES + SCAN_CHUNK - 1) / SCAN_CHUNK) // 74

// ---------------------------------------------------------------------------
// Both behaviors' degree histograms in one pass (R6 lesson: atomics spread
// over 150K addresses are fine; never funnel onto few counters).
__global__ void hist2_kernel(const int* __restrict__ colC,
                             const int* __restrict__ colR,
                             int* __restrict__ degC,
                             int* __restrict__ degR) {
    int stride = gridDim.x * blockDim.x;
    for (int e = blockIdx.x * blockDim.x + threadIdx.x; e < NUM_EDGES; e += stride) {
        atomicAdd(&degC[colC[e]], 1);
        atomicAdd(&degR[colR[e]], 1);
    }
}

// dinv for both behaviors
__global__ void dinv2_kernel(const int* __restrict__ degC,
                             const int* __restrict__ degR,
                             float* __restrict__ dinvC,
                             float* __restrict__ dinvR) {
    int stride = gridDim.x * blockDim.x;
    for (int i = blockIdx.x * blockDim.x + threadIdx.x; i < N_NODES; i += stride) {
        float dc = (float)degC[i];
        float dr = (float)degR[i];
        dinvC[i] = (dc > 0.0f) ? (1.0f / sqrtf(dc)) : 0.0f;
        dinvR[i] = (dr > 0.0f) ? (1.0f / sqrtf(dr)) : 0.0f;
    }
}

// ---- exclusive scans (both behaviors fused; C = blocks [0,74), R = [74,148))
__global__ void scanA2_kernel(const int* __restrict__ degC,
                              const int* __restrict__ degR,
                              int* __restrict__ cptrC,
                              int* __restrict__ cptrR,
                              int* __restrict__ bsum) {
    __shared__ int s[SCAN_THREADS];
    bool isR = blockIdx.x >= SCAN_NBLK;
    int b = isR ? (int)blockIdx.x - SCAN_NBLK : (int)blockIdx.x;
    const int* deg = isR ? degR : degC;
    int* cptr = isR ? cptrR : cptrC;
    int t = threadIdx.x;
    int base = b * SCAN_CHUNK + t * SCAN_ITEMS;
    int items[SCAN_ITEMS];
    int mysum = 0;
    #pragma unroll
    for (int j = 0; j < SCAN_ITEMS; ++j) {
        int idx = base + j;
        items[j] = (idx < N_NODES) ? deg[idx] : 0;
        mysum += items[j];
    }
    s[t] = mysum;
    __syncthreads();
    for (int off = 1; off < SCAN_THREADS; off <<= 1) {
        int v = (t >= off) ? s[t - off] : 0;
        __syncthreads();
        s[t] += v;
        __syncthreads();
    }
    int excl = s[t] - mysum;
    if (t == SCAN_THREADS - 1) bsum[blockIdx.x] = s[t];
    int run = excl;
    #pragma unroll
    for (int j = 0; j < SCAN_ITEMS; ++j) {
        int idx = base + j;
        if (idx < N_NODES) cptr[idx] = run;
        run += items[j];
    }
}

__global__ void scanB2_kernel(const int* __restrict__ bsum,
                              int* __restrict__ boff,
                              int* __restrict__ cptrC,
                              int* __restrict__ cptrR) {
    if (threadIdx.x == 0) {
        int run = 0;
        for (int b = 0; b < SCAN_NBLK; ++b) { boff[b] = run; run += bsum[b]; }
        cptrC[N_NODES] = run;
    } else if (threadIdx.x == 1) {
        int run = 0;
        for (int b = SCAN_NBLK; b < 2 * SCAN_NBLK; ++b) { boff[b] = run; run += bsum[b]; }
        cptrR[N_NODES] = run;
    }
}

__global__ void scanC2_kernel(int* __restrict__ cptrC,
                              int* __restrict__ cptrR,
                              int* __restrict__ cursC,
                              int* __restrict__ cursR,
                              const int* __restrict__ boff) {
    bool isR = blockIdx.x >= SCAN_NBLK;
    int b = isR ? (int)blockIdx.x - SCAN_NBLK : (int)blockIdx.x;
    int* cptr = isR ? cptrR : cptrC;
    int* curs = isR ? cursR : cursC;
    int off = boff[blockIdx.x];
    int t = threadIdx.x;
    int base = b * SCAN_CHUNK + t * SCAN_ITEMS;
    #pragma unroll
    for (int j = 0; j < SCAN_ITEMS; ++j) {
        int idx = base + j;
        if (idx < N_NODES) {
            int v = cptr[idx] + off;
            cptr[idx] = v;
            curs[idx] = v;
        }
    }
}

// Both behaviors' ticket scatters, even block-interleave (R7 lesson: never
// tail-append fused work). Payload is 4B row only — norm is factored out
// via feature pre-scaling, halving the random-write amplification.
__global__ void scatter2_kernel(const int* __restrict__ rowC,
                                const int* __restrict__ colC,
                                int* __restrict__ cursC,
                                int* __restrict__ edC,
                                const int* __restrict__ rowR,
                                const int* __restrict__ colR,
                                int* __restrict__ cursR,
                                int* __restrict__ edR) {
    bool isR = blockIdx.x & 1;
    int blk2 = blockIdx.x >> 1;
    int nb2  = gridDim.x >> 1;
    const int* row = isR ? rowR : rowC;
    const int* col = isR ? colR : colC;
    int* curs = isR ? cursR : cursC;
    int* ed   = isR ? edR  : edC;
    int stride = nb2 * blockDim.x;
    for (int e = blk2 * blockDim.x + threadIdx.x; e < NUM_EDGES; e += stride) {
        int c = col[e];
        int p = atomicAdd(&curs[c], 1);
        ed[p] = row[e];
    }
}

// XS[i] = dinvC[node] * x0[i]   (reads user/item inputs directly, no concat copy)
__global__ void prescale_kernel(const float4* __restrict__ ue,
                                const float4* __restrict__ ie,
                                const float* __restrict__ dinvC,
                                float4* __restrict__ xs) {
    int stride = gridDim.x * blockDim.x;
    const int n4 = N_NODES * 16;
    for (int i = blockIdx.x * blockDim.x + threadIdx.x; i < n4; i += stride) {
        int node = i >> 4;
        float d = dinvC[node];
        float4 v = (node < NUM_USERS) ? ue[i] : ie[i - NUM_USERS * 16];
        xs[i] = make_float4(d * v.x, d * v.y, d * v.z, d * v.w);
    }
}

// ---------------------------------------------------------------------------
// CSR gather conv: pure unweighted sum of pre-scaled rows (NO per-edge load
// besides the row index — R7 lesson), epilogue x dinv[node].
// Wave = 1 node; 8 groups x 8 lanes -> 8 edges in flight (2x the R5 MLP);
// each lane covers dims [8*l8, 8*l8+8) as 2 float4s.
// MODE 0: o1 = dc*acc, o2 = dc*dc*acc          (layer 1: H1 and scaled H1)
// MODE 1: o1 = (x0 + a1 + dc*acc)/3            (cart layer2+combine; x0 from ue/ie)
// MODE 2: o1 = a2 + (a0 + o1_own + dc*acc)/3   (rent layer2+final; o1 holds H1r)
template <int MODE>
__device__ __forceinline__ void conv_body(int blk,
                                          const float4* __restrict__ xin,
                                          const int* __restrict__ colptr,
                                          const int* __restrict__ edata,
                                          const float* __restrict__ dinv,
                                          float4* o1,
                                          float4* __restrict__ o2,
                                          const float4* __restrict__ a0,
                                          const float4* __restrict__ a1,
                                          const float4* __restrict__ a2,
                                          const float4* __restrict__ ue,
                                          const float4* __restrict__ ie) {
    int lane = threadIdx.x & 63;
    int node = blk * 4 + (threadIdx.x >> 6);
    if (node >= N_NODES) return;
    int grp = lane >> 3;          // 0..7: edge slot
    int l8  = lane & 7;           // dim sub-block
    int s = colptr[node];
    int t = colptr[node + 1];
    float4 acc0 = make_float4(0.f, 0.f, 0.f, 0.f);
    float4 acc1 = make_float4(0.f, 0.f, 0.f, 0.f);
    for (int e = s + grp; e < t; e += 8) {
        int r = edata[e];                          // 8 consecutive 4B: coalesced
        const float4* xp = xin + (size_t)r * 16 + l8 * 2;
        float4 v0 = xp[0];
        float4 v1 = xp[1];
        acc0.x += v0.x; acc0.y += v0.y; acc0.z += v0.z; acc0.w += v0.w;
        acc1.x += v1.x; acc1.y += v1.y; acc1.z += v1.z; acc1.w += v1.w;
    }
    #pragma unroll
    for (int m = 8; m <= 32; m <<= 1) {
        acc0.x += __shfl_xor(acc0.x, m); acc0.y += __shfl_xor(acc0.y, m);
        acc0.z += __shfl_xor(acc0.z, m); acc0.w += __shfl_xor(acc0.w, m);
        acc1.x += __shfl_xor(acc1.x, m); acc1.y += __shfl_xor(acc1.y, m);
        acc1.z += __shfl_xor(acc1.z, m); acc1.w += __shfl_xor(acc1.w, m);
    }
    if (grp == 0) {               // lanes 0..7 write the full 64-dim row
        float dc = dinv[node];
        int o = node * 16 + l8 * 2;
        if (MODE == 0) {
            float d2 = dc * dc;
            o1[o]     = make_float4(dc * acc0.x, dc * acc0.y, dc * acc0.z, dc * acc0.w);
            o1[o + 1] = make_float4(dc * acc1.x, dc * acc1.y, dc * acc1.z, dc * acc1.w);
            o2[o]     = make_float4(d2 * acc0.x, d2 * acc0.y, d2 * acc0.z, d2 * acc0.w);
            o2[o + 1] = make_float4(d2 * acc1.x, d2 * acc1.y, d2 * acc1.z, d2 * acc1.w);
        } else if (MODE == 1) {
            const float sc = 1.0f / 3.0f;
            float4 x0, x1;
            if (node < NUM_USERS) { x0 = ue[o]; x1 = ue[o + 1]; }
            else { x0 = ie[o - NUM_USERS * 16]; x1 = ie[o + 1 - NUM_USERS * 16]; }
            float4 h0 = a1[o], h1 = a1[o + 1];
            o1[o]     = make_float4((x0.x + h0.x + dc * acc0.x) * sc,
                                    (x0.y + h0.y + dc * acc0.y) * sc,
                                    (x0.z + h0.z + dc * acc0.z) * sc,
                                    (x0.w + h0.w + dc * acc0.w) * sc);
            o1[o + 1] = make_float4((x1.x + h1.x + dc * acc1.x) * sc,
                                    (x1.y + h1.y + dc * acc1.y) * sc,
                                    (x1.z + h1.z + dc * acc1.z) * sc,
                                    (x1.w + h1.w + dc * acc1.w) * sc);
        } else {
            const float sc = 1.0f / 3.0f;
            float4 p0 = a0[o], p1 = a0[o + 1];
            float4 h0 = o1[o], h1 = o1[o + 1];    // H1r parked in d_out (own index)
            float4 g0 = a2[o], g1 = a2[o + 1];
            o1[o]     = make_float4(g0.x + (p0.x + h0.x + dc * acc0.x) * sc,
                                    g0.y + (p0.y + h0.y + dc * acc0.y) * sc,
                                    g0.z + (p0.z + h0.z + dc * acc0.z) * sc,
                                    g0.w + (p0.w + h0.w + dc * acc0.w) * sc);
            o1[o + 1] = make_float4(g1.x + (p1.x + h1.x + dc * acc1.x) * sc,
                                    g1.y + (p1.y + h1.y + dc * acc1.y) * sc,
                                    g1.z + (p1.z + h1.z + dc * acc1.z) * sc,
                                    g1.w + (p1.w + h1.w + dc * acc1.w) * sc);
        }
    }
}

__global__ void conv1_kernel(const float4* __restrict__ xin,
                             const int* __restrict__ colptr,
                             const int* __restrict__ edata,
                             const float* __restrict__ dinv,
                             float4* __restrict__ oH,
                             float4* __restrict__ oHS) {
    conv_body<0>(blockIdx.x, xin, colptr, edata, dinv, oH, oHS,
                 nullptr, nullptr, nullptr, nullptr, nullptr);
}

__global__ void conv2c_kernel(const float4* __restrict__ xin,
                              const int* __restrict__ colptr,
                              const int* __restrict__ edata,
                              const float* __restrict__ dinv,
                              const float4* __restrict__ h1,
                              const float4* __restrict__ ue,
                              const float4* __restrict__ ie,
                              float4* __restrict__ cart) {
    conv_body<1>(blockIdx.x, xin, colptr, edata, dinv, cart, nullptr,
                 nullptr, h1, nullptr, ue, ie);
}

__global__ void conv2r_kernel(const float4* __restrict__ xin,
                              const int* __restrict__ colptr,
                              const int* __restrict__ edata,
                              const float* __restrict__ dinv,
                              const float4* __restrict__ x2,
                              const float4* __restrict__ cart,
                              float4* outp) {
    conv_body<2>(blockIdx.x, xin, colptr, edata, dinv, outp, nullptr,
                 x2, nullptr, cart, nullptr, nullptr);
}

// Wt[k][j] = W[j][k] for both weight matrices (single block)
__global__ void transpose_w_kernel(const float* __restrict__ Wu,
                                   const float* __restrict__ Wi,
                                   float* __restrict__ WtU,
                                   float* __restrict__ WtI) {
    for (int t = threadIdx.x; t < DIM * DIM; t += blockDim.x) {
        int j = t >> 6, k = t & 63;
        WtU[k * DIM + j] = Wu[t];
        WtI[k * DIM + j] = Wi[t];
    }
}

// dst = src @ Wt (per-row user/item); dsts = dinvR[i] * dst  (pre-scaled copy)
__global__ void matmul2_kernel(const float* __restrict__ src,
                               const float* __restrict__ WtU,
                               const float* __restrict__ WtI,
                               const float* __restrict__ dinvR,
                               float* __restrict__ dst,
                               float* __restrict__ dsts) {
    __shared__ float rows[4][DIM];
    int lane = threadIdx.x & 63;
    int g = threadIdx.x >> 6;
    int totalGroups = N_NODES / 4;
    for (int blk = blockIdx.x; blk < totalGroups; blk += gridDim.x) {
        int i = blk * 4 + g;
        rows[g][lane] = src[(size_t)i * DIM + lane];
        __syncthreads();
        const float* Wt = (i < NUM_USERS) ? WtU : WtI;
        float acc = 0.0f;
        #pragma unroll
        for (int k = 0; k < DIM; ++k)
            acc = fmaf(rows[g][k], Wt[k * DIM + lane], acc);
        dst[(size_t)i * DIM + lane]  = acc;
        dsts[(size_t)i * DIM + lane] = dinvR[i] * acc;
        __syncthreads();
    }
}

// ---------------------------------------------------------------------------
extern "C" void kernel_launch(void* const* d_in, const int* in_sizes, int n_in,
                              void* d_out, int out_size, void* d_ws, size_t ws_size,
                              hipStream_t stream) {
    const float* user_emb = (const float*)d_in[0];
    const float* item_emb = (const float*)d_in[1];
    const float* W_user   = (const float*)d_in[2];
    const float* W_item   = (const float*)d_in[3];
    const int*   ec       = (const int*)d_in[4];   // [2][NUM_EDGES]
    const int*   er       = (const int*)d_in[5];
    const int* cart_row = ec;
    const int* cart_col = ec + NUM_EDGES;
    const int* rent_row = er;
    const int* rent_col = er + NUM_EDGES;
    float* out = (float*)d_out;

    const size_t NV = (size_t)N_NODES * DIM;       // 9.6M floats
    float* ws    = (float*)d_ws;
    float* A     = ws;                  // XS (scaled x0), then X2 after matmul
    float* B     = A + NV;              // H1 (cart), then XS2 after matmul
    float* C     = B + NV;              // HS (cart), then HSr (rent)
    float* D     = C + NV;              // CART
    float* DINVC = D + NV;
    float* DINVR = DINVC + NPAD;
    int*   DEGC  = (int*)(DINVR + NPAD);
    int*   DEGR  = DEGC + NPAD;         // adjacent -> one memset covers both
    int*   CPTRC = DEGR + NPAD;
    int*   CURSC = CPTRC + NPAD;
    int*   CPTRR = CURSC + NPAD;
    int*   CURSR = CPTRR + NPAD;
    int*   BSUM  = CURSR + NPAD;        // 148 used
    int*   BOFF  = BSUM + 256;
    float* WtU   = (float*)(BOFF + 256);
    float* WtI   = WtU + DIM * DIM;
    int*   EDC   = (int*)(WtI + DIM * DIM);   // 2M int = 8 MB
    int*   EDR   = EDC + NUM_EDGES;

    const int BLOCKS = 2048, THREADS = 256;

    hipMemsetAsync(DEGC, 0, 2 * NPAD * sizeof(int), stream);
    transpose_w_kernel<<<1, 256, 0, stream>>>(W_user, W_item, WtU, WtI);

    // CSR build for both behaviors (fused pairwise)
    hist2_kernel<<<BLOCKS, THREADS, 0, stream>>>(cart_col, rent_col, DEGC, DEGR);
    dinv2_kernel<<<(N_NODES + 255) / 256, 256, 0, stream>>>(DEGC, DEGR, DINVC, DINVR);
    scanA2_kernel<<<2 * SCAN_NBLK, SCAN_THREADS, 0, stream>>>(DEGC, DEGR, CPTRC, CPTRR, BSUM);
    scanB2_kernel<<<1, 64, 0, stream>>>(BSUM, BOFF, CPTRC, CPTRR);
    scanC2_kernel<<<2 * SCAN_NBLK, SCAN_THREADS, 0, stream>>>(CPTRC, CPTRR, CURSC, CURSR, BOFF);
    scatter2_kernel<<<BLOCKS, THREADS, 0, stream>>>(cart_row, cart_col, CURSC, EDC,
                                                    rent_row, rent_col, CURSR, EDR);

    // XS = dinvC * concat(user_emb, item_emb)
    prescale_kernel<<<BLOCKS, THREADS, 0, stream>>>((const float4*)user_emb,
                                                    (const float4*)item_emb,
                                                    DINVC, (float4*)A);

    // cart: H1 = D^-1/2 A D^-1/2 X  (B), HS = dinvC*H1 (C)
    conv1_kernel<<<CONV_GRID, 256, 0, stream>>>((const float4*)A, CPTRC, EDC,
                                                DINVC, (float4*)B, (float4*)C);
    // CART = (X + H1 + conv(H1)) / 3
    conv2c_kernel<<<CONV_GRID, 256, 0, stream>>>((const float4*)C, CPTRC, EDC,
                                                 DINVC, (const float4*)B,
                                                 (const float4*)user_emb,
                                                 (const float4*)item_emb,
                                                 (float4*)D);

    // projection: X2 = CART @ W^T (A), XS2 = dinvR*X2 (B)
    matmul2_kernel<<<BLOCKS, THREADS, 0, stream>>>(D, WtU, WtI, DINVR, A, B);

    // rent: H1r -> d_out (parked), HSr -> C
    conv1_kernel<<<CONV_GRID, 256, 0, stream>>>((const float4*)B, CPTRR, EDR,
                                                DINVR, (float4*)out, (float4*)C);
    // out = CART + (X2 + H1r + conv(H1r)) / 3   (reads own-index H1r from d_out)
    conv2r_kernel<<<CONV_GRID, 256, 0, stream>>>((const float4*)C, CPTRR, EDR,
                                                 DINVR, (const float4*)A,
                                                 (const float4*)D, (float4*)out);
}